// Round 1
// baseline (564.824 us; speedup 1.0000x reference)
//
#include <hip/hip_runtime.h>
#include <hip/hip_bf16.h>
#include <stdint.h>

#define NEXP 64
#define TTOK 32768
#define HID  1024
#define IMID 512
#define CAP  1024

typedef __bf16 bf16x8 __attribute__((ext_vector_type(8)));
typedef float  f32x4  __attribute__((ext_vector_type(4)));

static __device__ __forceinline__ unsigned int f2bf_u(float f) {
    __hip_bfloat16 h = __float2bfloat16(f);
    return (unsigned int)*reinterpret_cast<unsigned short*>(&h);
}
static __device__ __forceinline__ unsigned int pack2(float lo, float hi) {
    return f2bf_u(lo) | (f2bf_u(hi) << 16);
}

// ---------------- GEMM1: X[cnt,1024] x W13[1024, 2*512] -> SwiGLU -> H bf16 [T,512]
__global__ __launch_bounds__(256, 2)
void moe_gemm1(const float* __restrict__ x,
               const int* __restrict__ tpe,
               const float* __restrict__ w13,
               __hip_bfloat16* __restrict__ hbuf) {
    const int nt = blockIdx.x;   // 0..3  (128 gate cols + 128 up cols)
    const int mt = blockIdx.y;   // 0..7
    const int e  = blockIdx.z;

    int cnt = tpe[e]; if (cnt > CAP) cnt = CAP;
    const int m0 = mt * 128;
    if (m0 >= cnt) return;
    int start = 0;
    for (int i = 0; i < e; ++i) start += tpe[i];

    __shared__ alignas(16) char As[128 * 128];  // [m 0..127][k 0..63] bf16, swizzled
    __shared__ alignas(16) char Bg[128 * 128];  // [n 0..127][k 0..63] bf16 (transposed w13 gate)
    __shared__ alignas(16) char Bu[128 * 128];  // up chunk

    const int tid  = threadIdx.x;
    const int lane = tid & 63;
    const int w    = tid >> 6;
    const int wr   = w >> 1, wc = w & 1;
    const int r    = lane & 15, q = lane >> 4;

    f32x4 accg[4][4], accu[4][4];
    const f32x4 z4 = {0.f, 0.f, 0.f, 0.f};
    #pragma unroll
    for (int i = 0; i < 4; ++i)
        #pragma unroll
        for (int j = 0; j < 4; ++j) { accg[i][j] = z4; accu[i][j] = z4; }

    // staging assignments
    const int arow = tid >> 4;                 // 0..15  (A rows, +16/pass)
    const int ac   = tid & 15;                 // A k-quad
    const int nrow = lane + ((w & 1) << 6);    // 0..127 (B transposed row = col n)
    const int kqb  = w >> 1;                   // 0..1   (B k-quad parity)

    const float* w13e = w13 + ((size_t)e << 20);          // e*1024*1024

    for (int kt = 0; kt < 16; ++kt) {
        __syncthreads();
        // ---- stage A (x rows, fp32 -> bf16) ----
        {
            const float* srcA = x + (size_t)(start + m0) * HID + kt * 64 + (ac << 2);
            #pragma unroll
            for (int p = 0; p < 8; ++p) {
                int m = arow + (p << 4);
                f32x4 v = z4;
                if (m0 + m < cnt) v = *reinterpret_cast<const f32x4*>(srcA + (size_t)m * HID);
                uint2 wv;
                wv.x = pack2(v.x, v.y);
                wv.y = pack2(v.z, v.w);
                *reinterpret_cast<uint2*>(As + m * 128 + (((ac << 3)) ^ ((m & 7) << 4))) = wv;
            }
        }
        // ---- stage B gate+up (column loads, transpose into LDS) ----
        {
            const float* srcB = w13e + (size_t)(kt * 64 + (kqb << 2)) * 1024 + nt * 128 + nrow;
            #pragma unroll
            for (int p = 0; p < 8; ++p) {
                int kq = kqb + (p << 1);
                const float* sg = srcB + (size_t)(p << 1) * 4096;   // advance 8 k-rows
                float g0 = sg[0],   g1 = sg[1024], g2 = sg[2048], g3 = sg[3072];
                float u0 = sg[512], u1 = sg[1536], u2 = sg[2560], u3 = sg[3584];
                uint2 wg, wu;
                wg.x = pack2(g0, g1); wg.y = pack2(g2, g3);
                wu.x = pack2(u0, u1); wu.y = pack2(u2, u3);
                int off = nrow * 128 + (((kq << 3)) ^ ((nrow & 7) << 4));
                *reinterpret_cast<uint2*>(Bg + off) = wg;
                *reinterpret_cast<uint2*>(Bu + off) = wu;
            }
        }
        __syncthreads();
        // ---- compute ----
        #pragma unroll
        for (int kk = 0; kk < 2; ++kk) {
            const int kbyte = (kk << 6) + (q << 4);
            bf16x8 af[4], bgf[4], buf4[4];
            #pragma unroll
            for (int fm = 0; fm < 4; ++fm) {
                int row = (wr << 6) + (fm << 4) + r;
                af[fm] = *reinterpret_cast<const bf16x8*>(As + row * 128 + (kbyte ^ ((row & 7) << 4)));
            }
            #pragma unroll
            for (int fn = 0; fn < 4; ++fn) {
                int row = (wc << 6) + (fn << 4) + r;
                int off = row * 128 + (kbyte ^ ((row & 7) << 4));
                bgf[fn]  = *reinterpret_cast<const bf16x8*>(Bg + off);
                buf4[fn] = *reinterpret_cast<const bf16x8*>(Bu + off);
            }
            #pragma unroll
            for (int fm = 0; fm < 4; ++fm)
                #pragma unroll
                for (int fn = 0; fn < 4; ++fn) {
                    accg[fm][fn] = __builtin_amdgcn_mfma_f32_16x16x32_bf16(af[fm], bgf[fn],  accg[fm][fn], 0, 0, 0);
                    accu[fm][fn] = __builtin_amdgcn_mfma_f32_16x16x32_bf16(af[fm], buf4[fn], accu[fm][fn], 0, 0, 0);
                }
        }
    }

    // ---- epilogue: SwiGLU, store bf16 H ----
    __hip_bfloat16* hb = hbuf + (size_t)start * IMID;
    #pragma unroll
    for (int fm = 0; fm < 4; ++fm) {
        int mb = m0 + (wr << 6) + (fm << 4) + (q << 2);
        #pragma unroll
        for (int fn = 0; fn < 4; ++fn) {
            int icol = (nt << 7) + (wc << 6) + (fn << 4) + r;
            #pragma unroll
            for (int v = 0; v < 4; ++v) {
                if (mb + v < cnt) {
                    float g = accg[fm][fn][v];
                    float u = accu[fm][fn][v];
                    float s = (g / (1.f + __expf(-g))) * u;
                    hb[(size_t)(mb + v) * IMID + icol] = __float2bfloat16(s);
                }
            }
        }
    }
}

// ---------------- GEMM2: H bf16 [cnt,512] x W2[512,1024] -> out fp32 [T,1024]
__global__ __launch_bounds__(256, 2)
void moe_gemm2(const __hip_bfloat16* __restrict__ hbuf,
               const int* __restrict__ tpe,
               const float* __restrict__ w2,
               float* __restrict__ out) {
    const int nt = blockIdx.x;   // 0..7
    const int mt = blockIdx.y;   // 0..7
    const int e  = blockIdx.z;

    int cnt = tpe[e]; if (cnt > CAP) cnt = CAP;
    const int m0 = mt * 128;
    if (m0 >= cnt) return;
    int start = 0;
    for (int i = 0; i < e; ++i) start += tpe[i];

    __shared__ alignas(16) char As[128 * 128];
    __shared__ alignas(16) char Bs[128 * 128];

    const int tid  = threadIdx.x;
    const int lane = tid & 63;
    const int w    = tid >> 6;
    const int wr   = w >> 1, wc = w & 1;
    const int r    = lane & 15, q = lane >> 4;

    f32x4 acc[4][4];
    const f32x4 z4 = {0.f, 0.f, 0.f, 0.f};
    #pragma unroll
    for (int i = 0; i < 4; ++i)
        #pragma unroll
        for (int j = 0; j < 4; ++j) acc[i][j] = z4;

    const int arow = tid >> 3;                 // 0..31
    const int ac8  = tid & 7;                  // k-oct (8 bf16)
    const int nrow = lane + ((w & 1) << 6);    // 0..127
    const int kqb  = w >> 1;

    const float* w2e = w2 + (size_t)e * IMID * HID;

    for (int kt = 0; kt < 8; ++kt) {
        __syncthreads();
        // ---- stage A (h rows, already bf16: raw 16B copies) ----
        {
            const __hip_bfloat16* srcA = hbuf + (size_t)(start + m0) * IMID + kt * 64 + (ac8 << 3);
            #pragma unroll
            for (int p = 0; p < 4; ++p) {
                int m = arow + (p << 5);
                uint4 v = {0u, 0u, 0u, 0u};
                if (m0 + m < cnt) v = *reinterpret_cast<const uint4*>(srcA + (size_t)m * IMID);
                *reinterpret_cast<uint4*>(As + m * 128 + (((ac8 << 4)) ^ ((m & 7) << 4))) = v;
            }
        }
        // ---- stage B (w2 column loads, transpose) ----
        {
            const float* srcB = w2e + (size_t)(kt * 64 + (kqb << 2)) * HID + nt * 128 + nrow;
            #pragma unroll
            for (int p = 0; p < 8; ++p) {
                int kq = kqb + (p << 1);
                const float* sb = srcB + (size_t)(p << 1) * 4096;
                float b0 = sb[0], b1 = sb[1024], b2 = sb[2048], b3 = sb[3072];
                uint2 wb;
                wb.x = pack2(b0, b1); wb.y = pack2(b2, b3);
                *reinterpret_cast<uint2*>(Bs + nrow * 128 + (((kq << 3)) ^ ((nrow & 7) << 4))) = wb;
            }
        }
        __syncthreads();
        // ---- compute ----
        #pragma unroll
        for (int kk = 0; kk < 2; ++kk) {
            const int kbyte = (kk << 6) + (q << 4);
            bf16x8 af[4], bf[4];
            #pragma unroll
            for (int fm = 0; fm < 4; ++fm) {
                int row = (wr << 6) + (fm << 4) + r;
                af[fm] = *reinterpret_cast<const bf16x8*>(As + row * 128 + (kbyte ^ ((row & 7) << 4)));
            }
            #pragma unroll
            for (int fn = 0; fn < 4; ++fn) {
                int row = (wc << 6) + (fn << 4) + r;
                bf[fn] = *reinterpret_cast<const bf16x8*>(Bs + row * 128 + (kbyte ^ ((row & 7) << 4)));
            }
            #pragma unroll
            for (int fm = 0; fm < 4; ++fm)
                #pragma unroll
                for (int fn = 0; fn < 4; ++fn)
                    acc[fm][fn] = __builtin_amdgcn_mfma_f32_16x16x32_bf16(af[fm], bf[fn], acc[fm][fn], 0, 0, 0);
        }
    }

    // ---- epilogue: fp32 out ----
    float* ob = out + (size_t)start * HID;
    #pragma unroll
    for (int fm = 0; fm < 4; ++fm) {
        int mb = m0 + (wr << 6) + (fm << 4) + (q << 2);
        #pragma unroll
        for (int fn = 0; fn < 4; ++fn) {
            int ocol = (nt << 7) + (wc << 6) + (fn << 4) + r;
            #pragma unroll
            for (int v = 0; v < 4; ++v) {
                if (mb + v < cnt)
                    ob[(size_t)(mb + v) * HID + ocol] = acc[fm][fn][v];
            }
        }
    }
}

extern "C" void kernel_launch(void* const* d_in, const int* in_sizes, int n_in,
                              void* d_out, int out_size, void* d_ws, size_t ws_size,
                              hipStream_t stream) {
    const float* x   = (const float*)d_in[0];
    const int*   tpe = (const int*)d_in[1];
    const float* w13 = (const float*)d_in[2];
    const float* w2  = (const float*)d_in[3];
    float* out = (float*)d_out;
    __hip_bfloat16* hbuf = (__hip_bfloat16*)d_ws;   // 32768*512*2 = 33.5 MB

    dim3 blk(256, 1, 1);
    moe_gemm1<<<dim3(4, 8, NEXP), blk, 0, stream>>>(x, tpe, w13, hbuf);
    moe_gemm2<<<dim3(8, 8, NEXP), blk, 0, stream>>>(hbuf, tpe, w2, out);
}

// Round 2
// 337.788 us; speedup vs baseline: 1.6721x; 1.6721x over previous
//
#include <hip/hip_runtime.h>
#include <hip/hip_bf16.h>
#include <stdint.h>

#define NEXP 64
#define TTOK 32768
#define HID  1024
#define IMID 512
#define CAP  1024

typedef __bf16 bf16x8 __attribute__((ext_vector_type(8)));
typedef float  f32x4  __attribute__((ext_vector_type(4)));

static __device__ __forceinline__ unsigned int f2bf_u(float f) {
    __hip_bfloat16 h = __float2bfloat16(f);
    return (unsigned int)*reinterpret_cast<unsigned short*>(&h);
}
static __device__ __forceinline__ unsigned int pack2(float lo, float hi) {
    return f2bf_u(lo) | (f2bf_u(hi) << 16);
}
static __device__ __forceinline__ unsigned short f2bf_s(float f) {
    __hip_bfloat16 h = __float2bfloat16(f);
    return *reinterpret_cast<unsigned short*>(&h);
}

static __device__ __forceinline__ void gload16(const void* g, void* l) {
    __builtin_amdgcn_global_load_lds(
        (const __attribute__((address_space(1))) unsigned int*)g,
        (__attribute__((address_space(3))) unsigned int*)l,
        16, 0, 0);
}

// ================= preprocessing =================

// x fp32 [T,1024] -> bf16 [T,1024]
__global__ __launch_bounds__(256)
void cvt_x_k(const float* __restrict__ x, unsigned short* __restrict__ xbf) {
    size_t i = ((size_t)blockIdx.x * 256 + threadIdx.x) * 8;
    f32x4 a = *reinterpret_cast<const f32x4*>(x + i);
    f32x4 b = *reinterpret_cast<const f32x4*>(x + i + 4);
    uint4 o;
    o.x = pack2(a.x, a.y); o.y = pack2(a.z, a.w);
    o.z = pack2(b.x, b.y); o.w = pack2(b.z, b.w);
    *reinterpret_cast<uint4*>(xbf + i) = o;
}

// weights fp32 [e][KROWS][1024] -> bf16 [e][1024 n'][KROWS], optionally pairing
// gate/up columns at 16-col granularity (for w13).
template<int KROWS, bool PAIR>
__global__ __launch_bounds__(256)
void cvt_w_k(const float* __restrict__ src_base, unsigned short* __restrict__ dst_base) {
    const int n0 = blockIdx.x * 64, k0 = blockIdx.y * 64, e = blockIdx.z;
    __shared__ unsigned short Tl[64][72];
    const int t = threadIdx.x;
    const int kl = t >> 4, nl = (t & 15) * 4;
    const float* src = src_base + (size_t)e * KROWS * 1024 + (size_t)k0 * 1024 + n0;
    #pragma unroll
    for (int p = 0; p < 4; ++p) {
        int k = kl + p * 16;
        f32x4 v = *reinterpret_cast<const f32x4*>(src + (size_t)k * 1024 + nl);
        uint2 w;
        w.x = pack2(v.x, v.y); w.y = pack2(v.z, v.w);
        *reinterpret_cast<uint2*>(&Tl[k][nl]) = w;
    }
    __syncthreads();
    const int nloc = t >> 2, kc = (t & 3) * 16;
    const int n = n0 + nloc;
    int np;
    if (PAIR) {
        int c = n & 511, isup = n >> 9;
        np = (c >> 4) * 32 + isup * 16 + (c & 15);
    } else {
        np = n;
    }
    unsigned int v32[8];
    #pragma unroll
    for (int j = 0; j < 8; ++j) {
        unsigned int lo = Tl[kc + 2 * j][nloc];
        unsigned int hi = Tl[kc + 2 * j + 1][nloc];
        v32[j] = lo | (hi << 16);
    }
    unsigned short* dst = dst_base + (size_t)e * 1024 * KROWS + (size_t)np * KROWS + k0 + kc;
    uint4 o0 = {v32[0], v32[1], v32[2], v32[3]};
    uint4 o1 = {v32[4], v32[5], v32[6], v32[7]};
    *reinterpret_cast<uint4*>(dst)     = o0;
    *reinterpret_cast<uint4*>(dst + 8) = o1;
}

// ================= GEMM1: xbf[cnt,1024] x w13p -> SwiGLU -> hbuf bf16 [T,512]
__global__ __launch_bounds__(256, 2)
void gemm1(const unsigned short* __restrict__ xbf,
           const int* __restrict__ tpe,
           const unsigned short* __restrict__ w13p,
           unsigned short* __restrict__ hbuf) {
    const int nt = blockIdx.x;   // 0..7 : n' rows [nt*128, +128) = 64 intermediate cols
    const int mt = blockIdx.y;   // 0..7
    const int e  = blockIdx.z;

    int cnt = tpe[e]; if (cnt > CAP) cnt = CAP;
    const int m0 = mt * 128;
    if (m0 >= cnt) return;
    int start = 0;
    for (int i = 0; i < e; ++i) start += tpe[i];

    __shared__ alignas(16) unsigned short As[128 * 64];
    __shared__ alignas(16) unsigned short Bs[128 * 64];

    const int tid  = threadIdx.x;
    const int lane = tid & 63;
    const int w    = tid >> 6;
    const int wr   = w >> 1, wc = w & 1;
    const int r    = lane & 15, q = lane >> 4;

    f32x4 acc[4][4];
    const f32x4 z4 = {0.f, 0.f, 0.f, 0.f};
    #pragma unroll
    for (int i = 0; i < 4; ++i)
        #pragma unroll
        for (int j = 0; j < 4; ++j) acc[i][j] = z4;

    const int srow = w * 32 + (lane >> 3);   // staged row (+i*8)
    const int skb  = (lane & 7) * 16;        // byte within 128B k-row

    const char* aP = (const char*)xbf;                                        // 2048B rows
    const char* bP = (const char*)w13p + ((size_t)e << 21) + ((size_t)nt << 18); // 2048B rows
    char* AsW = (char*)As + w * 4096;
    char* BsW = (char*)Bs + w * 4096;

    for (int kt = 0; kt < 16; ++kt) {
        __syncthreads();
        const int kofs = kt * 128;
        #pragma unroll
        for (int i = 0; i < 4; ++i) {
            long grow = (long)start + m0 + srow + i * 8;
            if (grow > TTOK - 1) grow = TTOK - 1;
            gload16(aP + grow * 2048 + kofs + skb, AsW + i * 1024);
            gload16(bP + (size_t)(srow + i * 8) * 2048 + kofs + skb, BsW + i * 1024);
        }
        __syncthreads();
        #pragma unroll
        for (int kk = 0; kk < 2; ++kk) {
            bf16x8 af[4], bf[4];
            #pragma unroll
            for (int fm = 0; fm < 4; ++fm) {
                int row = (wr << 6) + (fm << 4) + r;
                af[fm] = *reinterpret_cast<const bf16x8*>((const char*)As + row * 128 + kk * 64 + q * 16);
            }
            #pragma unroll
            for (int fn = 0; fn < 4; ++fn) {
                int row = (wc << 6) + (fn << 4) + r;
                bf[fn] = *reinterpret_cast<const bf16x8*>((const char*)Bs + row * 128 + kk * 64 + q * 16);
            }
            #pragma unroll
            for (int fm = 0; fm < 4; ++fm)
                #pragma unroll
                for (int fn = 0; fn < 4; ++fn)
                    acc[fm][fn] = __builtin_amdgcn_mfma_f32_16x16x32_bf16(af[fm], bf[fn], acc[fm][fn], 0, 0, 0);
        }
    }

    // epilogue: SwiGLU over paired n-frags (even=gate, odd=up)
    #pragma unroll
    for (int fm = 0; fm < 4; ++fm) {
        int mb = m0 + (wr << 6) + (fm << 4) + (q << 2);
        #pragma unroll
        for (int fp = 0; fp < 2; ++fp) {
            f32x4 g = acc[fm][2 * fp];
            f32x4 u = acc[fm][2 * fp + 1];
            int c = ((nt << 2) + (wc << 1) + fp) * 16 + r;
            #pragma unroll
            for (int v = 0; v < 4; ++v) {
                if (mb + v < cnt) {
                    float gv = g[v];
                    float s = (gv / (1.f + __expf(-gv))) * u[v];
                    hbuf[(size_t)(start + mb + v) * IMID + c] = f2bf_s(s);
                }
            }
        }
    }
}

// ================= GEMM2: hbuf[cnt,512] x w2p -> out fp32 [T,1024]
__global__ __launch_bounds__(256, 2)
void gemm2(const unsigned short* __restrict__ hbuf,
           const int* __restrict__ tpe,
           const unsigned short* __restrict__ w2p,
           float* __restrict__ out) {
    const int nt = blockIdx.x;   // 0..7
    const int mt = blockIdx.y;   // 0..7
    const int e  = blockIdx.z;

    int cnt = tpe[e]; if (cnt > CAP) cnt = CAP;
    const int m0 = mt * 128;
    if (m0 >= cnt) return;
    int start = 0;
    for (int i = 0; i < e; ++i) start += tpe[i];

    __shared__ alignas(16) unsigned short As[128 * 64];
    __shared__ alignas(16) unsigned short Bs[128 * 64];

    const int tid  = threadIdx.x;
    const int lane = tid & 63;
    const int w    = tid >> 6;
    const int wr   = w >> 1, wc = w & 1;
    const int r    = lane & 15, q = lane >> 4;

    f32x4 acc[4][4];
    const f32x4 z4 = {0.f, 0.f, 0.f, 0.f};
    #pragma unroll
    for (int i = 0; i < 4; ++i)
        #pragma unroll
        for (int j = 0; j < 4; ++j) acc[i][j] = z4;

    const int srow = w * 32 + (lane >> 3);
    const int skb  = (lane & 7) * 16;

    const char* aP = (const char*)hbuf;                                       // 1024B rows
    const char* bP = (const char*)w2p + ((size_t)e << 20) + ((size_t)nt << 17); // 1024B rows
    char* AsW = (char*)As + w * 4096;
    char* BsW = (char*)Bs + w * 4096;

    for (int kt = 0; kt < 8; ++kt) {
        __syncthreads();
        const int kofs = kt * 128;
        #pragma unroll
        for (int i = 0; i < 4; ++i) {
            long grow = (long)start + m0 + srow + i * 8;
            if (grow > TTOK - 1) grow = TTOK - 1;
            gload16(aP + grow * 1024 + kofs + skb, AsW + i * 1024);
            gload16(bP + (size_t)(srow + i * 8) * 1024 + kofs + skb, BsW + i * 1024);
        }
        __syncthreads();
        #pragma unroll
        for (int kk = 0; kk < 2; ++kk) {
            bf16x8 af[4], bf[4];
            #pragma unroll
            for (int fm = 0; fm < 4; ++fm) {
                int row = (wr << 6) + (fm << 4) + r;
                af[fm] = *reinterpret_cast<const bf16x8*>((const char*)As + row * 128 + kk * 64 + q * 16);
            }
            #pragma unroll
            for (int fn = 0; fn < 4; ++fn) {
                int row = (wc << 6) + (fn << 4) + r;
                bf[fn] = *reinterpret_cast<const bf16x8*>((const char*)Bs + row * 128 + kk * 64 + q * 16);
            }
            #pragma unroll
            for (int fm = 0; fm < 4; ++fm)
                #pragma unroll
                for (int fn = 0; fn < 4; ++fn)
                    acc[fm][fn] = __builtin_amdgcn_mfma_f32_16x16x32_bf16(af[fm], bf[fn], acc[fm][fn], 0, 0, 0);
        }
    }

    #pragma unroll
    for (int fm = 0; fm < 4; ++fm) {
        int mb = m0 + (wr << 6) + (fm << 4) + (q << 2);
        #pragma unroll
        for (int fn = 0; fn < 4; ++fn) {
            int ocol = (nt << 7) + (wc << 6) + (fn << 4) + r;
            #pragma unroll
            for (int v = 0; v < 4; ++v) {
                if (mb + v < cnt)
                    out[(size_t)(start + mb + v) * HID + ocol] = acc[fm][fn][v];
            }
        }
    }
}

// ================= fallback (round-1 kernels, used only if ws too small) ===
__global__ __launch_bounds__(256, 2)
void moe_gemm1_fb(const float* __restrict__ x, const int* __restrict__ tpe,
                  const float* __restrict__ w13, __hip_bfloat16* __restrict__ hbuf) {
    const int nt = blockIdx.x, mt = blockIdx.y, e = blockIdx.z;
    int cnt = tpe[e]; if (cnt > CAP) cnt = CAP;
    const int m0 = mt * 128;
    if (m0 >= cnt) return;
    int start = 0;
    for (int i = 0; i < e; ++i) start += tpe[i];
    __shared__ alignas(16) char As[128 * 128];
    __shared__ alignas(16) char Bg[128 * 128];
    __shared__ alignas(16) char Bu[128 * 128];
    const int tid = threadIdx.x, lane = tid & 63, w = tid >> 6;
    const int wr = w >> 1, wc = w & 1, r = lane & 15, q = lane >> 4;
    f32x4 accg[4][4], accu[4][4];
    const f32x4 z4 = {0.f, 0.f, 0.f, 0.f};
    for (int i = 0; i < 4; ++i)
        for (int j = 0; j < 4; ++j) { accg[i][j] = z4; accu[i][j] = z4; }
    const int arow = tid >> 4, ac = tid & 15;
    const int nrow = lane + ((w & 1) << 6), kqb = w >> 1;
    const float* w13e = w13 + ((size_t)e << 20);
    for (int kt = 0; kt < 16; ++kt) {
        __syncthreads();
        {
            const float* srcA = x + (size_t)(start + m0) * HID + kt * 64 + (ac << 2);
            #pragma unroll
            for (int p = 0; p < 8; ++p) {
                int m = arow + (p << 4);
                f32x4 v = z4;
                if (m0 + m < cnt) v = *reinterpret_cast<const f32x4*>(srcA + (size_t)m * HID);
                uint2 wv; wv.x = pack2(v.x, v.y); wv.y = pack2(v.z, v.w);
                *reinterpret_cast<uint2*>(As + m * 128 + (((ac << 3)) ^ ((m & 7) << 4))) = wv;
            }
        }
        {
            const float* srcB = w13e + (size_t)(kt * 64 + (kqb << 2)) * 1024 + nt * 128 + nrow;
            #pragma unroll
            for (int p = 0; p < 8; ++p) {
                int kq = kqb + (p << 1);
                const float* sg = srcB + (size_t)(p << 1) * 4096;
                float g0 = sg[0], g1 = sg[1024], g2 = sg[2048], g3 = sg[3072];
                float u0 = sg[512], u1 = sg[1536], u2 = sg[2560], u3 = sg[3584];
                uint2 wg, wu;
                wg.x = pack2(g0, g1); wg.y = pack2(g2, g3);
                wu.x = pack2(u0, u1); wu.y = pack2(u2, u3);
                int off = nrow * 128 + (((kq << 3)) ^ ((nrow & 7) << 4));
                *reinterpret_cast<uint2*>(Bg + off) = wg;
                *reinterpret_cast<uint2*>(Bu + off) = wu;
            }
        }
        __syncthreads();
        #pragma unroll
        for (int kk = 0; kk < 2; ++kk) {
            const int kbyte = (kk << 6) + (q << 4);
            bf16x8 af[4], bgf[4], buf4[4];
            #pragma unroll
            for (int fm = 0; fm < 4; ++fm) {
                int row = (wr << 6) + (fm << 4) + r;
                af[fm] = *reinterpret_cast<const bf16x8*>(As + row * 128 + (kbyte ^ ((row & 7) << 4)));
            }
            #pragma unroll
            for (int fn = 0; fn < 4; ++fn) {
                int row = (wc << 6) + (fn << 4) + r;
                int off = row * 128 + (kbyte ^ ((row & 7) << 4));
                bgf[fn] = *reinterpret_cast<const bf16x8*>(Bg + off);
                buf4[fn] = *reinterpret_cast<const bf16x8*>(Bu + off);
            }
            #pragma unroll
            for (int fm = 0; fm < 4; ++fm)
                #pragma unroll
                for (int fn = 0; fn < 4; ++fn) {
                    accg[fm][fn] = __builtin_amdgcn_mfma_f32_16x16x32_bf16(af[fm], bgf[fn], accg[fm][fn], 0, 0, 0);
                    accu[fm][fn] = __builtin_amdgcn_mfma_f32_16x16x32_bf16(af[fm], buf4[fn], accu[fm][fn], 0, 0, 0);
                }
        }
    }
    __hip_bfloat16* hb = (__hip_bfloat16*)hbuf + (size_t)start * IMID;
    #pragma unroll
    for (int fm = 0; fm < 4; ++fm) {
        int mb = m0 + (wr << 6) + (fm << 4) + (q << 2);
        #pragma unroll
        for (int fn = 0; fn < 4; ++fn) {
            int icol = (nt << 7) + (wc << 6) + (fn << 4) + r;
            #pragma unroll
            for (int v = 0; v < 4; ++v) {
                if (mb + v < cnt) {
                    float g = accg[fm][fn][v], u = accu[fm][fn][v];
                    float s = (g / (1.f + __expf(-g))) * u;
                    hb[(size_t)(mb + v) * IMID + icol] = __float2bfloat16(s);
                }
            }
        }
    }
}

__global__ __launch_bounds__(256, 2)
void moe_gemm2_fb(const __hip_bfloat16* __restrict__ hbuf, const int* __restrict__ tpe,
                  const float* __restrict__ w2, float* __restrict__ out) {
    const int nt = blockIdx.x, mt = blockIdx.y, e = blockIdx.z;
    int cnt = tpe[e]; if (cnt > CAP) cnt = CAP;
    const int m0 = mt * 128;
    if (m0 >= cnt) return;
    int start = 0;
    for (int i = 0; i < e; ++i) start += tpe[i];
    __shared__ alignas(16) char As[128 * 128];
    __shared__ alignas(16) char Bs[128 * 128];
    const int tid = threadIdx.x, lane = tid & 63, w = tid >> 6;
    const int wr = w >> 1, wc = w & 1, r = lane & 15, q = lane >> 4;
    f32x4 acc[4][4];
    const f32x4 z4 = {0.f, 0.f, 0.f, 0.f};
    for (int i = 0; i < 4; ++i)
        for (int j = 0; j < 4; ++j) acc[i][j] = z4;
    const int arow = tid >> 3, ac8 = tid & 7;
    const int nrow = lane + ((w & 1) << 6), kqb = w >> 1;
    const float* w2e = w2 + (size_t)e * IMID * HID;
    for (int kt = 0; kt < 8; ++kt) {
        __syncthreads();
        {
            const __hip_bfloat16* srcA = hbuf + (size_t)(start + m0) * IMID + kt * 64 + (ac8 << 3);
            #pragma unroll
            for (int p = 0; p < 4; ++p) {
                int m = arow + (p << 5);
                uint4 v = {0u, 0u, 0u, 0u};
                if (m0 + m < cnt) v = *reinterpret_cast<const uint4*>(srcA + (size_t)m * IMID);
                *reinterpret_cast<uint4*>(As + m * 128 + (((ac8 << 4)) ^ ((m & 7) << 4))) = v;
            }
        }
        {
            const float* srcB = w2e + (size_t)(kt * 64 + (kqb << 2)) * HID + nt * 128 + nrow;
            #pragma unroll
            for (int p = 0; p < 8; ++p) {
                int kq = kqb + (p << 1);
                const float* sb = srcB + (size_t)(p << 1) * 4096;
                float b0 = sb[0], b1 = sb[1024], b2 = sb[2048], b3 = sb[3072];
                uint2 wb; wb.x = pack2(b0, b1); wb.y = pack2(b2, b3);
                *reinterpret_cast<uint2*>(Bs + nrow * 128 + (((kq << 3)) ^ ((nrow & 7) << 4))) = wb;
            }
        }
        __syncthreads();
        #pragma unroll
        for (int kk = 0; kk < 2; ++kk) {
            const int kbyte = (kk << 6) + (q << 4);
            bf16x8 af[4], bf[4];
            #pragma unroll
            for (int fm = 0; fm < 4; ++fm) {
                int row = (wr << 6) + (fm << 4) + r;
                af[fm] = *reinterpret_cast<const bf16x8*>(As + row * 128 + (kbyte ^ ((row & 7) << 4)));
            }
            #pragma unroll
            for (int fn = 0; fn < 4; ++fn) {
                int row = (wc << 6) + (fn << 4) + r;
                bf[fn] = *reinterpret_cast<const bf16x8*>(Bs + row * 128 + (kbyte ^ ((row & 7) << 4)));
            }
            #pragma unroll
            for (int fm = 0; fm < 4; ++fm)
                #pragma unroll
                for (int fn = 0; fn < 4; ++fn)
                    acc[fm][fn] = __builtin_amdgcn_mfma_f32_16x16x32_bf16(af[fm], bf[fn], acc[fm][fn], 0, 0, 0);
        }
    }
    float* ob = out + (size_t)start * HID;
    #pragma unroll
    for (int fm = 0; fm < 4; ++fm) {
        int mb = m0 + (wr << 6) + (fm << 4) + (q << 2);
        #pragma unroll
        for (int fn = 0; fn < 4; ++fn) {
            int ocol = (nt << 7) + (wc << 6) + (fn << 4) + r;
            #pragma unroll
            for (int v = 0; v < 4; ++v) {
                if (mb + v < cnt)
                    ob[(size_t)(mb + v) * HID + ocol] = acc[fm][fn][v];
            }
        }
    }
}

extern "C" void kernel_launch(void* const* d_in, const int* in_sizes, int n_in,
                              void* d_out, int out_size, void* d_ws, size_t ws_size,
                              hipStream_t stream) {
    const float* x   = (const float*)d_in[0];
    const int*   tpe = (const int*)d_in[1];
    const float* w13 = (const float*)d_in[2];
    const float* w2  = (const float*)d_in[3];
    float* out = (float*)d_out;

    const size_t XBF_B  = (size_t)TTOK * HID * 2;        // 67,108,864
    const size_t HBUF_B = (size_t)TTOK * IMID * 2;       // 33,554,432
    const size_t W13P_B = (size_t)NEXP * HID * HID * 2;  // 134,217,728
    const size_t W2P_B  = (size_t)NEXP * HID * IMID * 2; // 67,108,864
    const size_t TOTAL  = XBF_B + HBUF_B + W13P_B + W2P_B;

    dim3 blk(256, 1, 1);
    if (ws_size >= TOTAL) {
        char* ws = (char*)d_ws;
        unsigned short* xbf  = (unsigned short*)(ws);
        unsigned short* hbuf = (unsigned short*)(ws + XBF_B);
        unsigned short* w13p = (unsigned short*)(ws + XBF_B + HBUF_B);
        unsigned short* w2p  = (unsigned short*)(ws + XBF_B + HBUF_B + W13P_B);

        cvt_x_k<<<dim3(16384, 1, 1), blk, 0, stream>>>(x, xbf);
        cvt_w_k<1024, true ><<<dim3(16, 16, NEXP), blk, 0, stream>>>(w13, w13p);
        cvt_w_k< 512, false><<<dim3(16,  8, NEXP), blk, 0, stream>>>(w2,  w2p);
        gemm1<<<dim3(8, 8, NEXP), blk, 0, stream>>>(xbf, tpe, w13p, hbuf);
        gemm2<<<dim3(8, 8, NEXP), blk, 0, stream>>>(hbuf, tpe, w2p, out);
    } else {
        __hip_bfloat16* hbuf = (__hip_bfloat16*)d_ws;
        moe_gemm1_fb<<<dim3(4, 8, NEXP), blk, 0, stream>>>(x, tpe, w13, hbuf);
        moe_gemm2_fb<<<dim3(8, 8, NEXP), blk, 0, stream>>>(hbuf, tpe, w2, out);
    }
}